// Round 23
// baseline (141.204 us; speedup 1.0000x reference)
//
#include <hip/hip_runtime.h>
#include <hip/hip_bf16.h>
#include <hip/hip_fp8.h>

typedef short short8 __attribute__((ext_vector_type(8)));
typedef float floatx4 __attribute__((ext_vector_type(4)));
typedef int intx8 __attribute__((ext_vector_type(8)));

constexpr int BATCH = 8, SEQ = 2048, DIMC = 512, HID = 1024, QKD = 128, NHID = 2176;
constexpr int TOK = BATCH * SEQ;

// workspace layout (bytes) — attention path all fp8; masked keys COMPACTED away
constexpr size_t OFF_XN8 = 0;                                    // [TOK][512] fp8
constexpr size_t OFF_WH8 = OFF_XN8 + (size_t)TOK * DIMC;         // [2176][512] fp8
constexpr size_t OFF_WO8 = OFF_WH8 + (size_t)NHID * DIMC;        // [512][1024] fp8 (Wo^T x 2^6)
constexpr size_t OFF_U8  = OFF_WO8 + (size_t)DIMC * HID;         // [TOK][1024] fp8 (u)
constexpr size_t OFF_V8  = OFF_U8  + (size_t)TOK * HID;          // [TOK][1024] fp8 (v, linear)
constexpr size_t OFF_BSE = OFF_V8  + (size_t)TOK * HID;          // [TOK][128] bf16 (base)
constexpr size_t OFF_Q8  = OFF_BSE + (size_t)TOK * QKD * 2;      // [TOK][128] fp8 (q x 16)
constexpr size_t OFF_K8C = OFF_Q8  + (size_t)TOK * QKD;          // [B][2048][128] fp8 (compacted; pads zeroed)
constexpr size_t OFF_VT8 = OFF_K8C + (size_t)TOK * QKD;          // [B][1024][2048] fp8 (V^T, compacted cols)
constexpr size_t OFF_P8  = OFF_VT8 + (size_t)BATCH * HID * SEQ;  // [B][2048][2048] fp8 (P x 2^20)
constexpr size_t OFF_HU8 = OFF_P8  + (size_t)BATCH * SEQ * SEQ;  // [TOK][1024] fp8 (hu x 2^16)
constexpr size_t OFF_CPS = OFF_HU8 + (size_t)TOK * HID;          // [B][2048] int
constexpr size_t OFF_IPS = OFF_CPS + (size_t)TOK * 4;            // [B][2048] int (inverse; pads 0)
constexpr size_t OFF_NTL = OFF_IPS + (size_t)TOK * 4;            // [B] int

__device__ inline void gload_lds16(const void* g, void* l) {
    __builtin_amdgcn_global_load_lds(
        (const __attribute__((address_space(1))) void*)g,
        (__attribute__((address_space(3))) void*)l, 16, 0, 0);
}

// ---- HW fp8 converters (gfx950: OCP e4m3fn; saturating). Fallback: header type. ----
#if __has_builtin(__builtin_amdgcn_cvt_pk_fp8_f32)
__device__ inline int cvtpk8(float a, float b) {
    return __builtin_amdgcn_cvt_pk_fp8_f32(a, b, 0, false);
}
__device__ inline unsigned char f2fp8(float v) {
    return (unsigned char)(cvtpk8(v, v) & 0xff);
}
#else
__device__ inline unsigned char f2fp8(float v) {
    __hip_fp8_e4m3 t(v); return t.__x;
}
__device__ inline int cvtpk8(float a, float b) {
    return (int)f2fp8(a) | ((int)f2fp8(b) << 8);
}
#endif
#if __has_builtin(__builtin_amdgcn_cvt_f32_fp8)
__device__ inline float fp82f(unsigned char b) {
    return __builtin_amdgcn_cvt_f32_fp8((int)b, 0);
}
#else
__device__ inline float fp82f(unsigned char b) {
    __hip_fp8_e4m3 t; t.__x = b; return (float)t;
}
#endif
__device__ inline float fast_rcp(float x) { return __builtin_amdgcn_rcpf(x); }
__device__ inline float fast_silu(float v) { return v * fast_rcp(1.0f + __expf(-v)); }

// ------- prep (merged): [0,8) mask scan | [8,8+4096) LayerNorm | rest weight cvt -------
constexpr int LN_BLOCKS = TOK / 4;                                  // 4096
constexpr int CVT_BLOCKS = (NHID * DIMC + DIMC * HID + 255) / 256;  // 6400
__global__ __launch_bounds__(256) void prep_kernel(const int* __restrict__ mask,
                                                   int* __restrict__ cpos,
                                                   int* __restrict__ ipos,
                                                   int* __restrict__ ntl,
                                                   unsigned char* __restrict__ k8c,
                                                   const float* __restrict__ x,
                                                   const float* __restrict__ lnw,
                                                   const float* __restrict__ lnb,
                                                   unsigned char* __restrict__ xn8,
                                                   const float* __restrict__ Wh,
                                                   const float* __restrict__ Wo,
                                                   unsigned char* __restrict__ WhT8,
                                                   unsigned char* __restrict__ WoT8) {
    if (blockIdx.x >= 8u && blockIdx.x < 8u + LN_BLOCKS) {
        // ---- LayerNorm: wave-per-row, float4 loads, shfl-only reduce ----
        int t = (blockIdx.x - 8) * 4 + (threadIdx.x >> 6);
        int lane = threadIdx.x & 63;
        const float* xr = x + (size_t)t * DIMC + lane * 8;
        float4 v0 = *(const float4*)xr;
        float4 v1 = *(const float4*)(xr + 4);
        float s = v0.x + v0.y + v0.z + v0.w + v1.x + v1.y + v1.z + v1.w;
        float ss = v0.x * v0.x + v0.y * v0.y + v0.z * v0.z + v0.w * v0.w
                 + v1.x * v1.x + v1.y * v1.y + v1.z * v1.z + v1.w * v1.w;
        #pragma unroll
        for (int o = 32; o; o >>= 1) { s += __shfl_down(s, o); ss += __shfl_down(ss, o); }
        s = __shfl(s, 0); ss = __shfl(ss, 0);
        float mu = s * (1.0f / DIMC);
        float inv = rsqrtf(ss * (1.0f / DIMC) - mu * mu + 1e-5f);
        int c = lane * 8;
        float4 w0 = *(const float4*)&lnw[c], w1 = *(const float4*)&lnw[c + 4];
        float4 b0 = *(const float4*)&lnb[c], b1 = *(const float4*)&lnb[c + 4];
        float y0 = (v0.x - mu) * inv * w0.x + b0.x;
        float y1 = (v0.y - mu) * inv * w0.y + b0.y;
        float y2 = (v0.z - mu) * inv * w0.z + b0.z;
        float y3 = (v0.w - mu) * inv * w0.w + b0.w;
        float y4 = (v1.x - mu) * inv * w1.x + b1.x;
        float y5 = (v1.y - mu) * inv * w1.y + b1.y;
        float y6 = (v1.z - mu) * inv * w1.z + b1.z;
        float y7 = (v1.w - mu) * inv * w1.w + b1.w;
        int p01 = cvtpk8(y0, y1), p23 = cvtpk8(y2, y3);
        int p45 = cvtpk8(y4, y5), p67 = cvtpk8(y6, y7);
        uint2 o2;
        o2.x = (unsigned)(p01 & 0xffff) | ((unsigned)(p23 & 0xffff) << 16);
        o2.y = (unsigned)(p45 & 0xffff) | ((unsigned)(p67 & 0xffff) << 16);
        *(uint2*)&xn8[(size_t)t * DIMC + c] = o2;
        return;
    }
    if (blockIdx.x >= 8u + LN_BLOCKS) {
        int i = (blockIdx.x - 8 - LN_BLOCKS) * 256 + threadIdx.x;
        const int total1 = NHID * DIMC;
        const int total2 = DIMC * HID;
        if (i < total1) {
            int n = i / DIMC, k = i % DIMC;
            WhT8[i] = f2fp8(Wh[(size_t)k * NHID + n]);
        } else if (i < total1 + total2) {
            int j = i - total1;
            int d = j / HID, h = j % HID;
            WoT8[j] = f2fp8(Wo[(size_t)h * DIMC + d] * 64.0f);
        }
        return;
    }
    int b = blockIdx.x;
    __shared__ int sh[256];
    __shared__ int base;
    if (threadIdx.x == 0) base = 0;
    __syncthreads();
    for (int c = 0; c < 8; c++) {
        int n = c * 256 + threadIdx.x;
        int um = (mask[(size_t)b * SEQ + n] == 0) ? 1 : 0;
        sh[threadIdx.x] = um;
        __syncthreads();
        for (int off = 1; off < 256; off <<= 1) {
            int v = (threadIdx.x >= off) ? sh[threadIdx.x - off] : 0;
            __syncthreads();
            sh[threadIdx.x] += v;
            __syncthreads();
        }
        int incl = sh[threadIdx.x];
        int cp = um ? (base + incl - 1) : -1;
        cpos[(size_t)b * SEQ + n] = cp;
        if (cp >= 0) ipos[(size_t)b * SEQ + cp] = n;
        __syncthreads();
        if (threadIdx.x == 255) base += incl;
        __syncthreads();
    }
    int cnt = base;
    int nt = (cnt + 127) >> 7;
    if (threadIdx.x == 0) ntl[b] = nt;
    for (int c = cnt + threadIdx.x; c < SEQ; c += 256)
        ipos[(size_t)b * SEQ + c] = 0;
    uint4 z = {0, 0, 0, 0};
    for (int r = cnt + threadIdx.x; r < nt * 128; r += 256) {
        uint4* p = (uint4*)&k8c[((size_t)b * SEQ + r) * QKD];
        #pragma unroll
        for (int j = 0; j < 8; j++) p[j] = z;
    }
}

// ------- merged: blocks [0,4096) q/k rotary | [4096,8192) compacting V transpose -------
__global__ __launch_bounds__(256) void qv_kernel(const __hip_bfloat16* __restrict__ bse,
                                                 const float* __restrict__ sn,
                                                 const float* __restrict__ cs,
                                                 const int* __restrict__ cpos,
                                                 const float* __restrict__ gamma,
                                                 const float* __restrict__ beta,
                                                 unsigned char* __restrict__ q8,
                                                 unsigned char* __restrict__ k8c,
                                                 const unsigned char* __restrict__ v8,
                                                 const int* __restrict__ ipos,
                                                 const int* __restrict__ ntl,
                                                 unsigned char* __restrict__ Vt8) {
    if (blockIdx.x < 4096) {
        int t = blockIdx.x * 4 + (threadIdx.x >> 6);
        int j = threadIdx.x & 63;
        const __hip_bfloat16* base = bse + (size_t)t * QKD;
        float b0 = __bfloat162float(base[2 * j]);
        float b1 = __bfloat162float(base[2 * j + 1]);
        float q0 = b0 * gamma[2 * j] + beta[2 * j];
        float q1 = b1 * gamma[2 * j + 1] + beta[2 * j + 1];
        float k0 = b0 * gamma[QKD + 2 * j] + beta[QKD + 2 * j];
        float k1 = b1 * gamma[QKD + 2 * j + 1] + beta[QKD + 2 * j + 1];
        float s = sn[(size_t)t * 64 + j];
        float c = cs[(size_t)t * 64 + j];
        int pq = cvtpk8((q0 * c - q1 * s) * 16.f, (q1 * c + q0 * s) * 16.f);
        q8[(size_t)t * QKD + j]      = (unsigned char)pq;
        q8[(size_t)t * QKD + 64 + j] = (unsigned char)(pq >> 8);
        int cp = cpos[t];
        if (cp >= 0) {
            int bb = t >> 11;
            int pk = cvtpk8((k0 * c - k1 * s) * 16.f, (k1 * c + k0 * s) * 16.f);
            size_t kr = ((size_t)bb * SEQ + cp) * QKD;
            k8c[kr + j]      = (unsigned char)pk;
            k8c[kr + 64 + j] = (unsigned char)(pk >> 8);
        }
        return;
    }
    int v = blockIdx.x - 4096;
    int b = v >> 9;
    int c0 = (v & 31) * 64, h0 = ((v >> 5) & 15) * 64;
    if (c0 >= (ntl[b] << 7)) return;
    __shared__ unsigned char tile[64][68];
    int r = threadIdx.x >> 4;
    int c4 = (threadIdx.x & 15) << 2;
    #pragma unroll
    for (int i = 0; i < 4; i++) {
        int rr = i * 16 + r;
        int src = ipos[(size_t)b * SEQ + c0 + rr];
        *(uchar4*)&tile[rr][c4] = *(const uchar4*)&v8[((size_t)b * SEQ + src) * HID + h0 + c4];
    }
    __syncthreads();
    #pragma unroll
    for (int i = 0; i < 4; i++) {
        int hh = i * 16 + r;
        uchar4 o;
        o.x = tile[c4][hh]; o.y = tile[c4 + 1][hh]; o.z = tile[c4 + 2][hh]; o.w = tile[c4 + 3][hh];
        *(uchar4*)&Vt8[((size_t)b * HID + h0 + hh) * SEQ + c0 + c4] = o;
    }
}

// ============ MX-fp8 GEMM: 128xBN tile, BK=128, mfma_scale 16x16x128, unit scales ============
// R23: + T5 s_setprio(1) around the MFMA cluster. Mechanism: at 4 blocks/CU the
// co-resident blocks sit at different loop phases (m114 overlap); setprio lets the
// MFMA-phase wave win issue arbitration over other blocks' staging-phase waves
// (inter-block role diversity = the attn/m191 regime, not the single-block lockstep
// null of m190). Bounded downside (~-1.5% worst case per m190).
// __launch_bounds__(256,4): proven config (VGPR 64, zero spill — R21's (256,5) spilled).
// EPI 0: silu(acc+bias) -> u8 | v8 | bse   EPI 1: P8 = relu(raw)^2*16
// EPI 2: hu8 = f2fp8(acc*oscale*u8)        EPI 3: out = acc*oscale + bias + Xres
// RAS 0: XCD m-stripe | RAS 1: batch=fid&7 ~ XCD
template <int EPI, int RAS, int BN>
__global__ __launch_bounds__(256, 4) void gemm_mx(
    const unsigned char* __restrict__ A, int lda, long long sA,
    const unsigned char* __restrict__ Bt, int ldb, long long sB,
    int K,
    const float* __restrict__ bias,
    const unsigned char* __restrict__ U8, int ldu, long long sU,
    const float* __restrict__ Xres, int ldx,
    float oscale,
    unsigned char* __restrict__ C8, int ldc8, long long sC8,
    unsigned char* __restrict__ V8out,
    __hip_bfloat16* __restrict__ Cbse,
    float* __restrict__ Cf, int ldcf,
    const int* __restrict__ ntl) {
    constexpr int NI = BN / 32;
    __shared__ unsigned char As[128 * 128];
    __shared__ unsigned char Bs[BN * 128];

    int m0, n0;
    if (RAS == 0) {
        int lin = blockIdx.x + gridDim.x * blockIdx.y;
        int xcd = lin & 7, j = lin >> 3;
        int gy = gridDim.y;
        m0 = (xcd * (gridDim.x >> 3) + j / gy) * 128;
        n0 = (j % gy) * BN;
    } else {
        int fid = blockIdx.x + gridDim.x * (blockIdx.y + gridDim.y * blockIdx.z);
        int b = fid & 7;
        int r = fid >> 3;
        int gy = gridDim.y;
        n0 = (r % gy) * BN;
        m0 = (r / gy) * 128;
        A += (size_t)b * sA;
        Bt += (size_t)b * sB;
        if (C8) C8 += (size_t)b * sC8;
        if (U8) U8 += (size_t)b * sU;
        if (EPI == 1 && n0 >= (ntl[b] << 7)) return;
        if (EPI == 2) K = ntl[b] << 7;
    }

    int tid = threadIdx.x, lane = tid & 63, wid = tid >> 6;
    int wr = (wid >> 1) * 64, wc = (wid & 1) * (BN / 2);
    int r16 = lane & 15, kq = lane >> 4;

    int srow = lane >> 3;
    int sc = (((lane & 7) ^ ((lane >> 3) & 7)) << 4);

    floatx4 acc[4][NI] = {};
    const int SCL = 0x7F7F7F7F;

    #define FRGRD(P, row, dst) { \
        uint4* p_ = (uint4*)&(dst); \
        p_[0] = *(const uint4*)&(P)[(row) * 128 + ((((kq * 2)     ^ ((row) & 7))) << 4)]; \
        p_[1] = *(const uint4*)&(P)[(row) * 128 + ((((kq * 2 + 1) ^ ((row) & 7))) << 4)]; }

    for (int kt = 0; kt < K; kt += 128) {
        #pragma unroll
        for (int i = 0; i < 4; i++) {
            int r0 = wid * 32 + i * 8;
            gload_lds16(&A[(size_t)(m0 + r0 + srow) * lda + kt + sc], &As[r0 * 128]);
        }
        #pragma unroll
        for (int i = 0; i < BN / 32; i++) {
            int r0 = wid * (BN / 4) + i * 8;
            gload_lds16(&Bt[(size_t)(n0 + r0 + srow) * ldb + kt + sc], &Bs[r0 * 128]);
        }
        __syncthreads();
        intx8 bfr[NI];
        #pragma unroll
        for (int ni = 0; ni < NI; ni++) FRGRD(Bs, wc + ni * 16 + r16, bfr[ni])
        __builtin_amdgcn_s_setprio(1);
        #pragma unroll
        for (int mo = 0; mo < 2; mo++) {
            intx8 afr[2];
            #pragma unroll
            for (int mi = 0; mi < 2; mi++) FRGRD(As, wr + (mo * 2 + mi) * 16 + r16, afr[mi])
            #pragma unroll
            for (int mi = 0; mi < 2; mi++)
                #pragma unroll
                for (int ni = 0; ni < NI; ni++)
                    acc[mo * 2 + mi][ni] = __builtin_amdgcn_mfma_scale_f32_16x16x128_f8f6f4(
                        afr[mi], bfr[ni], acc[mo * 2 + mi][ni], 0, 0, 0, SCL, 0, SCL);
        }
        __builtin_amdgcn_s_setprio(0);
        __syncthreads();
    }
    #undef FRGRD

    // epilogue: frag row=(lane>>4)*4+i, col=lane&15
    #pragma unroll
    for (int mi = 0; mi < 4; mi++) {
        #pragma unroll
        for (int ni = 0; ni < NI; ni++) {
            int rbase = m0 + wr + mi * 16 + kq * 4;
            int col = n0 + wc + ni * 16 + r16;
            if (EPI == 3) {
                #pragma unroll
                for (int i = 0; i < 4; i++) {
                    float v = acc[mi][ni][i] * oscale + bias[col] + Xres[(size_t)(rbase + i) * ldx + col];
                    Cf[(size_t)(rbase + i) * ldcf + col] = v;
                }
            } else {
                float e[4];
                #pragma unroll
                for (int i = 0; i < 4; i++) {
                    float v = acc[mi][ni][i];
                    if (EPI == 0) {
                        v = fast_silu(v + bias[col]);
                    } else if (EPI == 1) {
                        v = v > 0.0f ? v * v * 16.0f : 0.0f;
                    } else {
                        v *= oscale * fp82f(U8[(size_t)(rbase + i) * ldu + col]);
                    }
                    e[i] = v;
                }
                int p01 = cvtpk8(e[0], e[1]);
                int p23 = cvtpk8(e[2], e[3]);
                unsigned char byt[4] = {
                    (unsigned char)p01, (unsigned char)(p01 >> 8),
                    (unsigned char)p23, (unsigned char)(p23 >> 8)};
                if (EPI == 0) {
                    if (n0 < 1024) {
                        #pragma unroll
                        for (int i = 0; i < 4; i++)
                            C8[(size_t)(rbase + i) * HID + col] = byt[i];
                    } else if (n0 < 2048) {
                        #pragma unroll
                        for (int i = 0; i < 4; i++)
                            V8out[(size_t)(rbase + i) * HID + col - 1024] = byt[i];
                    } else {
                        #pragma unroll
                        for (int i = 0; i < 4; i++)
                            Cbse[(size_t)(rbase + i) * QKD + col - 2048] = __float2bfloat16(e[i]);
                    }
                } else {
                    #pragma unroll
                    for (int i = 0; i < 4; i++)
                        C8[(size_t)(rbase + i) * ldc8 + col] = byt[i];
                }
            }
        }
    }
}

extern "C" void kernel_launch(void* const* d_in, const int* in_sizes, int n_in,
                              void* d_out, int out_size, void* d_ws, size_t ws_size,
                              hipStream_t stream) {
    const float* x     = (const float*)d_in[0];
    const float* msin  = (const float*)d_in[1];
    const float* mcos  = (const float*)d_in[2];
    const int*   mask  = (const int*)d_in[3];
    const float* lnw   = (const float*)d_in[4];
    const float* lnb   = (const float*)d_in[5];
    const float* Wh    = (const float*)d_in[6];
    const float* bh    = (const float*)d_in[7];
    const float* gamma = (const float*)d_in[8];
    const float* beta  = (const float*)d_in[9];
    const float* Wo    = (const float*)d_in[10];
    const float* bo    = (const float*)d_in[11];
    float* out = (float*)d_out;
    char* ws = (char*)d_ws;

    unsigned char*  xn8  = (unsigned char*)(ws + OFF_XN8);
    unsigned char*  WhT8 = (unsigned char*)(ws + OFF_WH8);
    unsigned char*  WoT8 = (unsigned char*)(ws + OFF_WO8);
    unsigned char*  u8   = (unsigned char*)(ws + OFF_U8);
    unsigned char*  v8   = (unsigned char*)(ws + OFF_V8);
    __hip_bfloat16* bse  = (__hip_bfloat16*)(ws + OFF_BSE);
    unsigned char*  q8   = (unsigned char*)(ws + OFF_Q8);
    unsigned char*  k8c  = (unsigned char*)(ws + OFF_K8C);
    unsigned char*  Vt8  = (unsigned char*)(ws + OFF_VT8);
    unsigned char*  P8   = (unsigned char*)(ws + OFF_P8);
    unsigned char*  hu8  = (unsigned char*)(ws + OFF_HU8);
    int*            cpos = (int*)(ws + OFF_CPS);
    int*            ipos = (int*)(ws + OFF_IPS);
    int*            ntl  = (int*)(ws + OFF_NTL);

    // 0. prep (merged): mask scan | LayerNorm | weight convert
    prep_kernel<<<8 + LN_BLOCKS + CVT_BLOCKS, 256, 0, stream>>>(
        mask, cpos, ipos, ntl, k8c, x, lnw, lnb, xn8, Wh, Wo, WhT8, WoT8);

    // 1. GEMM1 (MX): silu(xn @ Wh + bh) -> u8 | v8 (linear) | bse
    gemm_mx<0, 0, 128><<<dim3(TOK / 128, NHID / 128), 256, 0, stream>>>(
        xn8, DIMC, 0, WhT8, DIMC, 0, DIMC, bh,
        nullptr, 0, 0, nullptr, 0, 0.0f,
        u8, 0, 0, v8, bse, nullptr, 0, nullptr);

    // 2. merged: q/k rotary (x16, compacted k) | compacting V transpose
    qv_kernel<<<8192, 256, 0, stream>>>(bse, msin, mcos, cpos, gamma, beta,
                                        q8, k8c, v8, ipos, ntl, Vt8);

    // 3. P8 = relu(q @ k8c^T)^2 * 2^20  per batch [K=128], batch ~ XCD
    gemm_mx<1, 1, 128><<<dim3(SEQ / 128, SEQ / 128, BATCH), 256, 0, stream>>>(
        q8, QKD, (long long)SEQ * QKD, k8c, QKD, (long long)SEQ * QKD, QKD, nullptr,
        nullptr, 0, 0, nullptr, 0, 0.0f,
        P8, SEQ, (long long)SEQ * SEQ, nullptr, nullptr, nullptr, 0, ntl);

    // 4. hu8 = (P8 @ Vt8) * 2^-19 * u  per batch [K = ntl*128 dynamic], batch ~ XCD
    gemm_mx<2, 1, 128><<<dim3(SEQ / 128, HID / 128, BATCH), 256, 0, stream>>>(
        P8, SEQ, (long long)SEQ * SEQ, Vt8, SEQ, (long long)HID * SEQ, SEQ, nullptr,
        u8, HID, (long long)SEQ * HID, nullptr, 0, 1.9073486328125e-06f /*2^-19*/,
        hu8, HID, (long long)SEQ * HID, nullptr, nullptr, nullptr, 0, ntl);

    // 5. out = hu8 @ WoT8 * 2^-22 + bo + x   [K=1024; BN=64 -> 1024 blocks]
    gemm_mx<3, 0, 64><<<dim3(TOK / 128, DIMC / 64), 256, 0, stream>>>(
        hu8, HID, 0, WoT8, HID, 0, HID, bo,
        nullptr, 0, 0, x, DIMC, 2.384185791015625e-07f /*2^-22*/,
        nullptr, 0, 0, nullptr, nullptr, out, DIMC, nullptr);
}

// Round 24
// 116.513 us; speedup vs baseline: 1.2119x; 1.2119x over previous
//
#include <hip/hip_runtime.h>
#include <hip/hip_bf16.h>
#include <hip/hip_fp8.h>

typedef short short8 __attribute__((ext_vector_type(8)));
typedef float floatx4 __attribute__((ext_vector_type(4)));
typedef int intx8 __attribute__((ext_vector_type(8)));

constexpr int BATCH = 8, SEQ = 2048, DIMC = 512, HID = 1024, QKD = 128, NHID = 2176;
constexpr int TOK = BATCH * SEQ;

// workspace layout (bytes) — attention path all fp8; masked keys COMPACTED away
constexpr size_t OFF_XN8 = 0;                                    // [TOK][512] fp8
constexpr size_t OFF_WH8 = OFF_XN8 + (size_t)TOK * DIMC;         // [2176][512] fp8
constexpr size_t OFF_WO8 = OFF_WH8 + (size_t)NHID * DIMC;        // [512][1024] fp8 (Wo^T x 2^6)
constexpr size_t OFF_U8  = OFF_WO8 + (size_t)DIMC * HID;         // [TOK][1024] fp8 (u)
constexpr size_t OFF_V8  = OFF_U8  + (size_t)TOK * HID;          // [TOK][1024] fp8 (v, linear)
constexpr size_t OFF_BSE = OFF_V8  + (size_t)TOK * HID;          // [TOK][128] bf16 (base)
constexpr size_t OFF_Q8  = OFF_BSE + (size_t)TOK * QKD * 2;      // [TOK][128] fp8 (q x 16)
constexpr size_t OFF_K8C = OFF_Q8  + (size_t)TOK * QKD;          // [B][2048][128] fp8 (compacted; pads zeroed)
constexpr size_t OFF_VT8 = OFF_K8C + (size_t)TOK * QKD;          // [B][1024][2048] fp8 (V^T, compacted cols)
constexpr size_t OFF_P8  = OFF_VT8 + (size_t)BATCH * HID * SEQ;  // [B][2048][2048] fp8 (P x 2^20)
constexpr size_t OFF_HU8 = OFF_P8  + (size_t)BATCH * SEQ * SEQ;  // [TOK][1024] fp8 (hu x 2^16)
constexpr size_t OFF_CPS = OFF_HU8 + (size_t)TOK * HID;          // [B][2048] int
constexpr size_t OFF_IPS = OFF_CPS + (size_t)TOK * 4;            // [B][2048] int (inverse; pads 0)
constexpr size_t OFF_NTL = OFF_IPS + (size_t)TOK * 4;            // [B] int

__device__ inline void gload_lds16(const void* g, void* l) {
    __builtin_amdgcn_global_load_lds(
        (const __attribute__((address_space(1))) void*)g,
        (__attribute__((address_space(3))) void*)l, 16, 0, 0);
}

// ---- HW fp8 converters (gfx950: OCP e4m3fn; saturating). Fallback: header type. ----
#if __has_builtin(__builtin_amdgcn_cvt_pk_fp8_f32)
__device__ inline int cvtpk8(float a, float b) {
    return __builtin_amdgcn_cvt_pk_fp8_f32(a, b, 0, false);
}
__device__ inline unsigned char f2fp8(float v) {
    return (unsigned char)(cvtpk8(v, v) & 0xff);
}
#else
__device__ inline unsigned char f2fp8(float v) {
    __hip_fp8_e4m3 t(v); return t.__x;
}
__device__ inline int cvtpk8(float a, float b) {
    return (int)f2fp8(a) | ((int)f2fp8(b) << 8);
}
#endif
#if __has_builtin(__builtin_amdgcn_cvt_f32_fp8)
__device__ inline float fp82f(unsigned char b) {
    return __builtin_amdgcn_cvt_f32_fp8((int)b, 0);
}
#else
__device__ inline float fp82f(unsigned char b) {
    __hip_fp8_e4m3 t; t.__x = b; return (float)t;
}
#endif
__device__ inline float fast_rcp(float x) { return __builtin_amdgcn_rcpf(x); }
__device__ inline float fast_silu(float v) { return v * fast_rcp(1.0f + __expf(-v)); }

// ------- prep (merged): [0,8) mask scan | [8,8+4096) LayerNorm | rest weight cvt -------
constexpr int LN_BLOCKS = TOK / 4;                                  // 4096
constexpr int CVT_BLOCKS = (NHID * DIMC + DIMC * HID + 255) / 256;  // 6400
__global__ __launch_bounds__(256) void prep_kernel(const int* __restrict__ mask,
                                                   int* __restrict__ cpos,
                                                   int* __restrict__ ipos,
                                                   int* __restrict__ ntl,
                                                   unsigned char* __restrict__ k8c,
                                                   const float* __restrict__ x,
                                                   const float* __restrict__ lnw,
                                                   const float* __restrict__ lnb,
                                                   unsigned char* __restrict__ xn8,
                                                   const float* __restrict__ Wh,
                                                   const float* __restrict__ Wo,
                                                   unsigned char* __restrict__ WhT8,
                                                   unsigned char* __restrict__ WoT8) {
    if (blockIdx.x >= 8u && blockIdx.x < 8u + LN_BLOCKS) {
        // ---- LayerNorm: wave-per-row, float4 loads, shfl-only reduce ----
        int t = (blockIdx.x - 8) * 4 + (threadIdx.x >> 6);
        int lane = threadIdx.x & 63;
        const float* xr = x + (size_t)t * DIMC + lane * 8;
        float4 v0 = *(const float4*)xr;
        float4 v1 = *(const float4*)(xr + 4);
        float s = v0.x + v0.y + v0.z + v0.w + v1.x + v1.y + v1.z + v1.w;
        float ss = v0.x * v0.x + v0.y * v0.y + v0.z * v0.z + v0.w * v0.w
                 + v1.x * v1.x + v1.y * v1.y + v1.z * v1.z + v1.w * v1.w;
        #pragma unroll
        for (int o = 32; o; o >>= 1) { s += __shfl_down(s, o); ss += __shfl_down(ss, o); }
        s = __shfl(s, 0); ss = __shfl(ss, 0);
        float mu = s * (1.0f / DIMC);
        float inv = rsqrtf(ss * (1.0f / DIMC) - mu * mu + 1e-5f);
        int c = lane * 8;
        float4 w0 = *(const float4*)&lnw[c], w1 = *(const float4*)&lnw[c + 4];
        float4 b0 = *(const float4*)&lnb[c], b1 = *(const float4*)&lnb[c + 4];
        float y0 = (v0.x - mu) * inv * w0.x + b0.x;
        float y1 = (v0.y - mu) * inv * w0.y + b0.y;
        float y2 = (v0.z - mu) * inv * w0.z + b0.z;
        float y3 = (v0.w - mu) * inv * w0.w + b0.w;
        float y4 = (v1.x - mu) * inv * w1.x + b1.x;
        float y5 = (v1.y - mu) * inv * w1.y + b1.y;
        float y6 = (v1.z - mu) * inv * w1.z + b1.z;
        float y7 = (v1.w - mu) * inv * w1.w + b1.w;
        int p01 = cvtpk8(y0, y1), p23 = cvtpk8(y2, y3);
        int p45 = cvtpk8(y4, y5), p67 = cvtpk8(y6, y7);
        uint2 o2;
        o2.x = (unsigned)(p01 & 0xffff) | ((unsigned)(p23 & 0xffff) << 16);
        o2.y = (unsigned)(p45 & 0xffff) | ((unsigned)(p67 & 0xffff) << 16);
        *(uint2*)&xn8[(size_t)t * DIMC + c] = o2;
        return;
    }
    if (blockIdx.x >= 8u + LN_BLOCKS) {
        int i = (blockIdx.x - 8 - LN_BLOCKS) * 256 + threadIdx.x;
        const int total1 = NHID * DIMC;
        const int total2 = DIMC * HID;
        if (i < total1) {
            int n = i / DIMC, k = i % DIMC;
            WhT8[i] = f2fp8(Wh[(size_t)k * NHID + n]);
        } else if (i < total1 + total2) {
            int j = i - total1;
            int d = j / HID, h = j % HID;
            WoT8[j] = f2fp8(Wo[(size_t)h * DIMC + d] * 64.0f);
        }
        return;
    }
    int b = blockIdx.x;
    __shared__ int sh[256];
    __shared__ int base;
    if (threadIdx.x == 0) base = 0;
    __syncthreads();
    for (int c = 0; c < 8; c++) {
        int n = c * 256 + threadIdx.x;
        int um = (mask[(size_t)b * SEQ + n] == 0) ? 1 : 0;
        sh[threadIdx.x] = um;
        __syncthreads();
        for (int off = 1; off < 256; off <<= 1) {
            int v = (threadIdx.x >= off) ? sh[threadIdx.x - off] : 0;
            __syncthreads();
            sh[threadIdx.x] += v;
            __syncthreads();
        }
        int incl = sh[threadIdx.x];
        int cp = um ? (base + incl - 1) : -1;
        cpos[(size_t)b * SEQ + n] = cp;
        if (cp >= 0) ipos[(size_t)b * SEQ + cp] = n;
        __syncthreads();
        if (threadIdx.x == 255) base += incl;
        __syncthreads();
    }
    int cnt = base;
    int nt = (cnt + 127) >> 7;
    if (threadIdx.x == 0) ntl[b] = nt;
    for (int c = cnt + threadIdx.x; c < SEQ; c += 256)
        ipos[(size_t)b * SEQ + c] = 0;
    uint4 z = {0, 0, 0, 0};
    for (int r = cnt + threadIdx.x; r < nt * 128; r += 256) {
        uint4* p = (uint4*)&k8c[((size_t)b * SEQ + r) * QKD];
        #pragma unroll
        for (int j = 0; j < 8; j++) p[j] = z;
    }
}

// ------- merged: blocks [0,4096) q/k rotary | [4096,8192) compacting V transpose -------
__global__ __launch_bounds__(256) void qv_kernel(const __hip_bfloat16* __restrict__ bse,
                                                 const float* __restrict__ sn,
                                                 const float* __restrict__ cs,
                                                 const int* __restrict__ cpos,
                                                 const float* __restrict__ gamma,
                                                 const float* __restrict__ beta,
                                                 unsigned char* __restrict__ q8,
                                                 unsigned char* __restrict__ k8c,
                                                 const unsigned char* __restrict__ v8,
                                                 const int* __restrict__ ipos,
                                                 const int* __restrict__ ntl,
                                                 unsigned char* __restrict__ Vt8) {
    if (blockIdx.x < 4096) {
        int t = blockIdx.x * 4 + (threadIdx.x >> 6);
        int j = threadIdx.x & 63;
        const __hip_bfloat16* base = bse + (size_t)t * QKD;
        float b0 = __bfloat162float(base[2 * j]);
        float b1 = __bfloat162float(base[2 * j + 1]);
        float q0 = b0 * gamma[2 * j] + beta[2 * j];
        float q1 = b1 * gamma[2 * j + 1] + beta[2 * j + 1];
        float k0 = b0 * gamma[QKD + 2 * j] + beta[QKD + 2 * j];
        float k1 = b1 * gamma[QKD + 2 * j + 1] + beta[QKD + 2 * j + 1];
        float s = sn[(size_t)t * 64 + j];
        float c = cs[(size_t)t * 64 + j];
        int pq = cvtpk8((q0 * c - q1 * s) * 16.f, (q1 * c + q0 * s) * 16.f);
        q8[(size_t)t * QKD + j]      = (unsigned char)pq;
        q8[(size_t)t * QKD + 64 + j] = (unsigned char)(pq >> 8);
        int cp = cpos[t];
        if (cp >= 0) {
            int bb = t >> 11;
            int pk = cvtpk8((k0 * c - k1 * s) * 16.f, (k1 * c + k0 * s) * 16.f);
            size_t kr = ((size_t)bb * SEQ + cp) * QKD;
            k8c[kr + j]      = (unsigned char)pk;
            k8c[kr + 64 + j] = (unsigned char)(pk >> 8);
        }
        return;
    }
    int v = blockIdx.x - 4096;
    int b = v >> 9;
    int c0 = (v & 31) * 64, h0 = ((v >> 5) & 15) * 64;
    if (c0 >= (ntl[b] << 7)) return;
    __shared__ unsigned char tile[64][68];
    int r = threadIdx.x >> 4;
    int c4 = (threadIdx.x & 15) << 2;
    #pragma unroll
    for (int i = 0; i < 4; i++) {
        int rr = i * 16 + r;
        int src = ipos[(size_t)b * SEQ + c0 + rr];
        *(uchar4*)&tile[rr][c4] = *(const uchar4*)&v8[((size_t)b * SEQ + src) * HID + h0 + c4];
    }
    __syncthreads();
    #pragma unroll
    for (int i = 0; i < 4; i++) {
        int hh = i * 16 + r;
        uchar4 o;
        o.x = tile[c4][hh]; o.y = tile[c4 + 1][hh]; o.z = tile[c4 + 2][hh]; o.w = tile[c4 + 3][hh];
        *(uchar4*)&Vt8[((size_t)b * HID + h0 + hh) * SEQ + c0 + c4] = o;
    }
}

// ============ MX-fp8 GEMM: 128xBN tile, BK=128, mfma_scale 16x16x128, unit scales ============
// R24 = R22 exactly (setprio REVERTED: R23 showed it starves co-resident blocks'
// staging issue and serializes the CU — -21%). This engine's throughput comes from
// cross-block wave overlap at 4 blocks/CU (m114); all probed perturbations of this
// design point regress or are neutral. __launch_bounds__(256,4): VGPR 64, zero spill.
// EPI 0: silu(acc+bias) -> u8 | v8 | bse   EPI 1: P8 = relu(raw)^2*16
// EPI 2: hu8 = f2fp8(acc*oscale*u8)        EPI 3: out = acc*oscale + bias + Xres
// RAS 0: XCD m-stripe | RAS 1: batch=fid&7 ~ XCD
template <int EPI, int RAS, int BN>
__global__ __launch_bounds__(256, 4) void gemm_mx(
    const unsigned char* __restrict__ A, int lda, long long sA,
    const unsigned char* __restrict__ Bt, int ldb, long long sB,
    int K,
    const float* __restrict__ bias,
    const unsigned char* __restrict__ U8, int ldu, long long sU,
    const float* __restrict__ Xres, int ldx,
    float oscale,
    unsigned char* __restrict__ C8, int ldc8, long long sC8,
    unsigned char* __restrict__ V8out,
    __hip_bfloat16* __restrict__ Cbse,
    float* __restrict__ Cf, int ldcf,
    const int* __restrict__ ntl) {
    constexpr int NI = BN / 32;
    __shared__ unsigned char As[128 * 128];
    __shared__ unsigned char Bs[BN * 128];

    int m0, n0;
    if (RAS == 0) {
        int lin = blockIdx.x + gridDim.x * blockIdx.y;
        int xcd = lin & 7, j = lin >> 3;
        int gy = gridDim.y;
        m0 = (xcd * (gridDim.x >> 3) + j / gy) * 128;
        n0 = (j % gy) * BN;
    } else {
        int fid = blockIdx.x + gridDim.x * (blockIdx.y + gridDim.y * blockIdx.z);
        int b = fid & 7;
        int r = fid >> 3;
        int gy = gridDim.y;
        n0 = (r % gy) * BN;
        m0 = (r / gy) * 128;
        A += (size_t)b * sA;
        Bt += (size_t)b * sB;
        if (C8) C8 += (size_t)b * sC8;
        if (U8) U8 += (size_t)b * sU;
        if (EPI == 1 && n0 >= (ntl[b] << 7)) return;
        if (EPI == 2) K = ntl[b] << 7;
    }

    int tid = threadIdx.x, lane = tid & 63, wid = tid >> 6;
    int wr = (wid >> 1) * 64, wc = (wid & 1) * (BN / 2);
    int r16 = lane & 15, kq = lane >> 4;

    int srow = lane >> 3;
    int sc = (((lane & 7) ^ ((lane >> 3) & 7)) << 4);

    floatx4 acc[4][NI] = {};
    const int SCL = 0x7F7F7F7F;

    #define FRGRD(P, row, dst) { \
        uint4* p_ = (uint4*)&(dst); \
        p_[0] = *(const uint4*)&(P)[(row) * 128 + ((((kq * 2)     ^ ((row) & 7))) << 4)]; \
        p_[1] = *(const uint4*)&(P)[(row) * 128 + ((((kq * 2 + 1) ^ ((row) & 7))) << 4)]; }

    for (int kt = 0; kt < K; kt += 128) {
        #pragma unroll
        for (int i = 0; i < 4; i++) {
            int r0 = wid * 32 + i * 8;
            gload_lds16(&A[(size_t)(m0 + r0 + srow) * lda + kt + sc], &As[r0 * 128]);
        }
        #pragma unroll
        for (int i = 0; i < BN / 32; i++) {
            int r0 = wid * (BN / 4) + i * 8;
            gload_lds16(&Bt[(size_t)(n0 + r0 + srow) * ldb + kt + sc], &Bs[r0 * 128]);
        }
        __syncthreads();
        intx8 bfr[NI];
        #pragma unroll
        for (int ni = 0; ni < NI; ni++) FRGRD(Bs, wc + ni * 16 + r16, bfr[ni])
        #pragma unroll
        for (int mo = 0; mo < 2; mo++) {
            intx8 afr[2];
            #pragma unroll
            for (int mi = 0; mi < 2; mi++) FRGRD(As, wr + (mo * 2 + mi) * 16 + r16, afr[mi])
            #pragma unroll
            for (int mi = 0; mi < 2; mi++)
                #pragma unroll
                for (int ni = 0; ni < NI; ni++)
                    acc[mo * 2 + mi][ni] = __builtin_amdgcn_mfma_scale_f32_16x16x128_f8f6f4(
                        afr[mi], bfr[ni], acc[mo * 2 + mi][ni], 0, 0, 0, SCL, 0, SCL);
        }
        __syncthreads();
    }
    #undef FRGRD

    // epilogue: frag row=(lane>>4)*4+i, col=lane&15
    #pragma unroll
    for (int mi = 0; mi < 4; mi++) {
        #pragma unroll
        for (int ni = 0; ni < NI; ni++) {
            int rbase = m0 + wr + mi * 16 + kq * 4;
            int col = n0 + wc + ni * 16 + r16;
            if (EPI == 3) {
                #pragma unroll
                for (int i = 0; i < 4; i++) {
                    float v = acc[mi][ni][i] * oscale + bias[col] + Xres[(size_t)(rbase + i) * ldx + col];
                    Cf[(size_t)(rbase + i) * ldcf + col] = v;
                }
            } else {
                float e[4];
                #pragma unroll
                for (int i = 0; i < 4; i++) {
                    float v = acc[mi][ni][i];
                    if (EPI == 0) {
                        v = fast_silu(v + bias[col]);
                    } else if (EPI == 1) {
                        v = v > 0.0f ? v * v * 16.0f : 0.0f;
                    } else {
                        v *= oscale * fp82f(U8[(size_t)(rbase + i) * ldu + col]);
                    }
                    e[i] = v;
                }
                int p01 = cvtpk8(e[0], e[1]);
                int p23 = cvtpk8(e[2], e[3]);
                unsigned char byt[4] = {
                    (unsigned char)p01, (unsigned char)(p01 >> 8),
                    (unsigned char)p23, (unsigned char)(p23 >> 8)};
                if (EPI == 0) {
                    if (n0 < 1024) {
                        #pragma unroll
                        for (int i = 0; i < 4; i++)
                            C8[(size_t)(rbase + i) * HID + col] = byt[i];
                    } else if (n0 < 2048) {
                        #pragma unroll
                        for (int i = 0; i < 4; i++)
                            V8out[(size_t)(rbase + i) * HID + col - 1024] = byt[i];
                    } else {
                        #pragma unroll
                        for (int i = 0; i < 4; i++)
                            Cbse[(size_t)(rbase + i) * QKD + col - 2048] = __float2bfloat16(e[i]);
                    }
                } else {
                    #pragma unroll
                    for (int i = 0; i < 4; i++)
                        C8[(size_t)(rbase + i) * ldc8 + col] = byt[i];
                }
            }
        }
    }
}

extern "C" void kernel_launch(void* const* d_in, const int* in_sizes, int n_in,
                              void* d_out, int out_size, void* d_ws, size_t ws_size,
                              hipStream_t stream) {
    const float* x     = (const float*)d_in[0];
    const float* msin  = (const float*)d_in[1];
    const float* mcos  = (const float*)d_in[2];
    const int*   mask  = (const int*)d_in[3];
    const float* lnw   = (const float*)d_in[4];
    const float* lnb   = (const float*)d_in[5];
    const float* Wh    = (const float*)d_in[6];
    const float* bh    = (const float*)d_in[7];
    const float* gamma = (const float*)d_in[8];
    const float* beta  = (const float*)d_in[9];
    const float* Wo    = (const float*)d_in[10];
    const float* bo    = (const float*)d_in[11];
    float* out = (float*)d_out;
    char* ws = (char*)d_ws;

    unsigned char*  xn8  = (unsigned char*)(ws + OFF_XN8);
    unsigned char*  WhT8 = (unsigned char*)(ws + OFF_WH8);
    unsigned char*  WoT8 = (unsigned char*)(ws + OFF_WO8);
    unsigned char*  u8   = (unsigned char*)(ws + OFF_U8);
    unsigned char*  v8   = (unsigned char*)(ws + OFF_V8);
    __hip_bfloat16* bse  = (__hip_bfloat16*)(ws + OFF_BSE);
    unsigned char*  q8   = (unsigned char*)(ws + OFF_Q8);
    unsigned char*  k8c  = (unsigned char*)(ws + OFF_K8C);
    unsigned char*  Vt8  = (unsigned char*)(ws + OFF_VT8);
    unsigned char*  P8   = (unsigned char*)(ws + OFF_P8);
    unsigned char*  hu8  = (unsigned char*)(ws + OFF_HU8);
    int*            cpos = (int*)(ws + OFF_CPS);
    int*            ipos = (int*)(ws + OFF_IPS);
    int*            ntl  = (int*)(ws + OFF_NTL);

    // 0. prep (merged): mask scan | LayerNorm | weight convert
    prep_kernel<<<8 + LN_BLOCKS + CVT_BLOCKS, 256, 0, stream>>>(
        mask, cpos, ipos, ntl, k8c, x, lnw, lnb, xn8, Wh, Wo, WhT8, WoT8);

    // 1. GEMM1 (MX): silu(xn @ Wh + bh) -> u8 | v8 (linear) | bse
    gemm_mx<0, 0, 128><<<dim3(TOK / 128, NHID / 128), 256, 0, stream>>>(
        xn8, DIMC, 0, WhT8, DIMC, 0, DIMC, bh,
        nullptr, 0, 0, nullptr, 0, 0.0f,
        u8, 0, 0, v8, bse, nullptr, 0, nullptr);

    // 2. merged: q/k rotary (x16, compacted k) | compacting V transpose
    qv_kernel<<<8192, 256, 0, stream>>>(bse, msin, mcos, cpos, gamma, beta,
                                        q8, k8c, v8, ipos, ntl, Vt8);

    // 3. P8 = relu(q @ k8c^T)^2 * 2^20  per batch [K=128], batch ~ XCD
    gemm_mx<1, 1, 128><<<dim3(SEQ / 128, SEQ / 128, BATCH), 256, 0, stream>>>(
        q8, QKD, (long long)SEQ * QKD, k8c, QKD, (long long)SEQ * QKD, QKD, nullptr,
        nullptr, 0, 0, nullptr, 0, 0.0f,
        P8, SEQ, (long long)SEQ * SEQ, nullptr, nullptr, nullptr, 0, ntl);

    // 4. hu8 = (P8 @ Vt8) * 2^-19 * u  per batch [K = ntl*128 dynamic], batch ~ XCD
    gemm_mx<2, 1, 128><<<dim3(SEQ / 128, HID / 128, BATCH), 256, 0, stream>>>(
        P8, SEQ, (long long)SEQ * SEQ, Vt8, SEQ, (long long)HID * SEQ, SEQ, nullptr,
        u8, HID, (long long)SEQ * HID, nullptr, 0, 1.9073486328125e-06f /*2^-19*/,
        hu8, HID, (long long)SEQ * HID, nullptr, nullptr, nullptr, 0, ntl);

    // 5. out = hu8 @ WoT8 * 2^-22 + bo + x   [K=1024; BN=64 -> 1024 blocks]
    gemm_mx<3, 0, 64><<<dim3(TOK / 128, DIMC / 64), 256, 0, stream>>>(
        hu8, HID, 0, WoT8, HID, 0, HID, bo,
        nullptr, 0, 0, x, DIMC, 2.384185791015625e-07f /*2^-22*/,
        nullptr, 0, 0, nullptr, nullptr, out, DIMC, nullptr);
}